// Round 3
// baseline (209.089 us; speedup 1.0000x reference)
//
#include <hip/hip_runtime.h>
#include <math.h>

#define BB 512
#define SS 128
#define KK 4
#define HH 128
#define DD 512   // K*H

typedef __attribute__((ext_vector_type(8))) short bf16x8;
typedef __attribute__((ext_vector_type(4))) float f32x4;

__device__ __forceinline__ unsigned short f2bf(float f) {
  unsigned u = __float_as_uint(f);
  unsigned r = u + 0x7fffu + ((u >> 16) & 1u);   // RNE (no NaNs in this data)
  return (unsigned short)(r >> 16);
}
__device__ __forceinline__ float bfhi(unsigned u) { return __uint_as_float(u & 0xffff0000u); }
__device__ __forceinline__ float bflo(unsigned u) { return __uint_as_float(u << 16); }
__device__ __forceinline__ unsigned pk2(float a, float b) {
  return (unsigned)f2bf(a) | ((unsigned)f2bf(b) << 16);
}

// ---------------------------------------------------------------------------
// hat[b][k][s][h'] = sum_h item[b][s][h] * w[s][k*HH+h'][h]
// fp32 inputs, bf16 output. One s + 128x128 tile per block; K=128 staged in
// two 64-wide halves, fp32->bf16 conversion fused into staging.
// LDS: flat 128x64 bf16 per array, XOR-swizzled granules (g+row)&7 ->
// staging writes and frag reads both conflict-free, 16B aligned, 32KB total.
// MFMA operands: A=w rows (d), B=item rows (b)  =>  D row=d, col=b, so the
// 4 acc regs are 4 consecutive h' -> ushort4 packed stores.
// ---------------------------------------------------------------------------
__global__ __launch_bounds__(256) void einsum_mfma(
    const float* __restrict__ A,            // item fp32 [B][S][H]
    const float* __restrict__ W,            // w    fp32 [S][D][H]
    unsigned short* __restrict__ hat)       // bf16 [B][K][S][H]
{
  __shared__ unsigned short Al[128 * 64];
  __shared__ unsigned short Wl[128 * 64];
  const int s  = blockIdx.z;
  const int b0 = blockIdx.x * 128;
  const int dt = blockIdx.y;
  const int d0 = dt * 128;
  const int t  = threadIdx.x;
  const int lane = t & 63, wv = t >> 6;
  const int qm = wv & 1, qn = wv >> 1;         // wave quadrant (64x64)
  const int n16 = lane & 15, kq = lane >> 4;
  const int r = t >> 1, cq = t & 1;            // staging: row / 32-col half

  f32x4 acc[4][4] = {};

  for (int ks = 0; ks < 128; ks += 64) {
    const float* ga = A + ((size_t)(b0 + r) * SS + s) * HH + ks + cq * 32;
    const float* gw = W + ((size_t)s * DD + d0 + r) * HH + ks + cq * 32;
    #pragma unroll
    for (int j = 0; j < 4; j++) {
      float4 a0 = *(const float4*)(ga + 8 * j);
      float4 a1 = *(const float4*)(ga + 8 * j + 4);
      float4 w0 = *(const float4*)(gw + 8 * j);
      float4 w1 = *(const float4*)(gw + 8 * j + 4);
      const int goff = ((cq * 4 + j + r) & 7) * 8;   // swizzled granule (8 bf16)
      uint4 pa, pw;
      pa.x = pk2(a0.x, a0.y); pa.y = pk2(a0.z, a0.w);
      pa.z = pk2(a1.x, a1.y); pa.w = pk2(a1.z, a1.w);
      pw.x = pk2(w0.x, w0.y); pw.y = pk2(w0.z, w0.w);
      pw.z = pk2(w1.x, w1.y); pw.w = pk2(w1.z, w1.w);
      *(uint4*)&Al[r * 64 + goff] = pa;
      *(uint4*)&Wl[r * 64 + goff] = pw;
    }
    __syncthreads();
    #pragma unroll
    for (int kk = 0; kk < 2; kk++) {
      bf16x8 af[4], bfr[4];
      #pragma unroll
      for (int i = 0; i < 4; i++) {
        const int ra = qm * 64 + i * 16 + n16;   // w rows (d)
        const int rb = qn * 64 + i * 16 + n16;   // item rows (b)
        af[i]  = *(const bf16x8*)&Wl[ra * 64 + ((kk * 4 + kq + ra) & 7) * 8];
        bfr[i] = *(const bf16x8*)&Al[rb * 64 + ((kk * 4 + kq + rb) & 7) * 8];
      }
      #pragma unroll
      for (int i = 0; i < 4; i++)
        #pragma unroll
        for (int j = 0; j < 4; j++)
          acc[i][j] = __builtin_amdgcn_mfma_f32_16x16x32_bf16(af[i], bfr[j], acc[i][j], 0, 0, 0);
    }
    __syncthreads();
  }

  // epilogue: D row (A=w) = qm*64+i*16+kq*4+reg = h'; col (B=item) = qn*64+j*16+n16 = b
  #pragma unroll
  for (int j = 0; j < 4; j++) {
    const int b = b0 + qn * 64 + j * 16 + n16;
    unsigned short* orow = hat + (((size_t)b * KK + dt) * SS + s) * HH;
    #pragma unroll
    for (int i = 0; i < 4; i++) {
      const int h = qm * 64 + i * 16 + kq * 4;
      ushort4 o;
      o.x = f2bf(acc[i][j][0]); o.y = f2bf(acc[i][j][1]);
      o.z = f2bf(acc[i][j][2]); o.w = f2bf(acc[i][j][3]);
      *(ushort4*)(orow + h) = o;
    }
  }
}

// ---------------------------------------------------------------------------
// Batch-axis softmax (legacy torch dim=0) + mask zeroing. Grid (S,K).
// ---------------------------------------------------------------------------
__global__ __launch_bounds__(256) void softmax_k(
    const float* __restrict__ cw, const float* __restrict__ mask,
    float* __restrict__ sw)
{
  __shared__ float rbuf[4];
  const int s = blockIdx.x, k = blockIdx.y, t = threadIdx.x;
  const size_t base = ((size_t)k * SS + s) * BB;
  float v0 = cw[base + t], v1 = cw[base + 256 + t];
  float m = fmaxf(v0, v1);
  #pragma unroll
  for (int o = 32; o; o >>= 1) m = fmaxf(m, __shfl_xor(m, o));
  if ((t & 63) == 0) rbuf[t >> 6] = m;
  __syncthreads();
  m = fmaxf(fmaxf(rbuf[0], rbuf[1]), fmaxf(rbuf[2], rbuf[3]));
  float e0 = expf(v0 - m), e1 = expf(v1 - m);
  float ssum = e0 + e1;
  #pragma unroll
  for (int o = 32; o; o >>= 1) ssum += __shfl_xor(ssum, o);
  __syncthreads();
  if ((t & 63) == 0) rbuf[t >> 6] = ssum;
  __syncthreads();
  float inv = 1.f / (rbuf[0] + rbuf[1] + rbuf[2] + rbuf[3]);
  float m0 = mask[(size_t)t * SS + s];
  float m1 = mask[(size_t)(t + 256) * SS + s];
  sw[base + t]       = (m0 == 0.f) ? 0.f : e0 * inv;
  sw[base + 256 + t] = (m1 == 0.f) ? 0.f : e1 * inv;
}

// ---------------------------------------------------------------------------
// One routing iteration per (b,k). Stream bf16 hat from L2/L3 (phase1
// coalesced over h, phase2 row-dot per s). Tiny LDS -> high occupancy.
//   mode 0: uniform sw from mask, cw  = delta
//   mode 1: sw from sw_in,        cw += delta
//   mode 2: sw from sw_in,        out = squash(cap)
// ---------------------------------------------------------------------------
__global__ __launch_bounds__(256) void routing_k(
    const unsigned short* __restrict__ hat, const float* __restrict__ mask,
    const float* __restrict__ sw_in, float* __restrict__ cw,
    float* __restrict__ out, int mode)
{
  __shared__ float sw_l[128];
  __shared__ float4 red4[8][33];
  __shared__ float cq_l[128];
  const int b = blockIdx.x, k = blockIdx.y, t = threadIdx.x;

  if (t < 128) {
    if (mode == 0) {
      sw_l[t] = (mask[(size_t)b * SS + t] == 0.f) ? 0.f : (1.f / 512.f);
    } else {
      sw_l[t] = sw_in[((size_t)k * SS + t) * BB + b];
    }
  }
  __syncthreads();

  const unsigned short* hrow = hat + ((size_t)b * KK + k) * SS * HH;

  // phase 1: cap[h] = sum_s sw[s] * hat[s][h]
  {
    const int h4 = t & 31, sg = t >> 5;
    const uint2* hp = (const uint2*)hrow;
    float4 a = make_float4(0.f, 0.f, 0.f, 0.f);
    #pragma unroll 4
    for (int i = 0; i < 16; i++) {
      int s = sg * 16 + i;
      uint2 v = hp[s * 32 + h4];
      float wv = sw_l[s];
      a.x = fmaf(wv, bflo(v.x), a.x);
      a.y = fmaf(wv, bfhi(v.x), a.y);
      a.z = fmaf(wv, bflo(v.y), a.z);
      a.w = fmaf(wv, bfhi(v.y), a.w);
    }
    red4[sg][h4] = a;
  }
  __syncthreads();

  if (t < 32) {
    float4 cap = red4[0][t];
    #pragma unroll
    for (int sg = 1; sg < 8; sg++) {
      float4 r = red4[sg][t];
      cap.x += r.x; cap.y += r.y; cap.z += r.z; cap.w += r.w;
    }
    float sq = cap.x * cap.x + cap.y * cap.y + cap.z * cap.z + cap.w * cap.w;
    #pragma unroll
    for (int o = 16; o; o >>= 1) sq += __shfl_xor(sq, o);
    const float n = sq;
    const float fac = n / (1.f + n) / sqrtf(n + 1e-9f);
    cap.x *= fac; cap.y *= fac; cap.z *= fac; cap.w *= fac;
    ((float4*)cq_l)[t] = cap;
    if (mode == 2)
      ((float4*)(out + ((size_t)b * KK + k) * HH))[t] = cap;
  }
  __syncthreads();

  if (mode < 2) {
    // phase 2: delta[s] = dot(hat[s][:], cq) — lane pair per s
    const int s = t >> 1, hh = t & 1;
    const uint4* hp16 = (const uint4*)hrow;
    float d = 0.f;
    #pragma unroll
    for (int j = 0; j < 8; j++) {
      uint4 v = hp16[s * 16 + hh * 8 + j];
      const float* cq = cq_l + hh * 64 + j * 8;
      d += bflo(v.x) * cq[0] + bfhi(v.x) * cq[1]
         + bflo(v.y) * cq[2] + bfhi(v.y) * cq[3]
         + bflo(v.z) * cq[4] + bfhi(v.z) * cq[5]
         + bflo(v.w) * cq[6] + bfhi(v.w) * cq[7];
    }
    d += __shfl_xor(d, 1);
    if (hh == 0) {
      float* p = cw + ((size_t)k * SS + s) * BB + b;
      if (mode == 0) *p = d; else *p += d;
    }
  }
}

extern "C" void kernel_launch(void* const* d_in, const int* in_sizes, int n_in,
                              void* d_out, int out_size, void* d_ws, size_t ws_size,
                              hipStream_t stream) {
  const float* item_eb = (const float*)d_in[0];   // [B,S,H]
  const float* mask    = (const float*)d_in[1];   // [B,S]
  const float* w       = (const float*)d_in[2];   // [1,S,K*H,H]
  float* out = (float*)d_out;                     // [B,K,H]

  char* ws = (char*)d_ws;
  unsigned short* hat_bf = (unsigned short*)ws;        // 67.1 MB bf16 [B][K][S][H]
  float* cw  = (float*)(ws + 67108864);                // 1 MB [K][S][B]
  float* swb = (float*)(ws + 68157440);                // 1 MB [K][S][B]

  einsum_mfma<<<dim3(4, 4, 128), 256, 0, stream>>>(item_eb, w, hat_bf);

  routing_k<<<dim3(BB, KK), 256, 0, stream>>>(hat_bf, mask, nullptr, cw, out, 0);
  softmax_k<<<dim3(SS, KK), 256, 0, stream>>>(cw, mask, swb);
  routing_k<<<dim3(BB, KK), 256, 0, stream>>>(hat_bf, mask, swb, cw, out, 1);
  softmax_k<<<dim3(SS, KK), 256, 0, stream>>>(cw, mask, swb);
  routing_k<<<dim3(BB, KK), 256, 0, stream>>>(hat_bf, mask, swb, cw, out, 2);
}

// Round 5
// 184.641 us; speedup vs baseline: 1.1324x; 1.1324x over previous
//
#include <hip/hip_runtime.h>
#include <math.h>

#define BB 512
#define SS 128
#define KK 4
#define HH 128
#define DD 512   // K*H

typedef __attribute__((ext_vector_type(8))) short bf16x8;
typedef __attribute__((ext_vector_type(4))) float f32x4;

__device__ __forceinline__ unsigned short f2bf(float f) {
  unsigned u = __float_as_uint(f);
  unsigned r = u + 0x7fffu + ((u >> 16) & 1u);   // RNE (no NaNs in this data)
  return (unsigned short)(r >> 16);
}
__device__ __forceinline__ float bfhi(unsigned u) { return __uint_as_float(u & 0xffff0000u); }
__device__ __forceinline__ float bflo(unsigned u) { return __uint_as_float(u << 16); }

// ---------------------------------------------------------------------------
// prep: item[b][s][h] fp32 -> item_t[s][b][h] bf16 (h-rows intact, so both
// sides fully coalesced), and w fp32 -> bf16 flat.
// Blocks 0..8191: item (8 rows each). Blocks 8192..9215: w (2048 float4 each).
// ---------------------------------------------------------------------------
__global__ __launch_bounds__(256) void prep_k(
    const float* __restrict__ item, const float* __restrict__ w,
    unsigned short* __restrict__ item_t, unsigned short* __restrict__ w_bf)
{
  const int blk = blockIdx.x, t = threadIdx.x;
  if (blk < 8192) {
    const int rid = blk * 8 + (t >> 5);       // rid = b*SS + s
    const int b = rid >> 7, s = rid & 127;
    const int c = t & 31;
    float4 v = ((const float4*)(item + (size_t)rid * HH))[c];
    ushort4 o;
    o.x = f2bf(v.x); o.y = f2bf(v.y); o.z = f2bf(v.z); o.w = f2bf(v.w);
    ((ushort4*)(item_t + ((size_t)s * BB + b) * HH))[c] = o;
  } else {
    size_t base = (size_t)(blk - 8192) * 2048 + t;
    const float4* src = (const float4*)w;
    ushort4* dst = (ushort4*)w_bf;
    #pragma unroll
    for (int j = 0; j < 8; j++) {
      float4 v = src[base + 256 * j];
      ushort4 o;
      o.x = f2bf(v.x); o.y = f2bf(v.y); o.z = f2bf(v.z); o.w = f2bf(v.w);
      dst[base + 256 * j] = o;
    }
  }
}

// ---------------------------------------------------------------------------
// hat[b][k][s][h'] = sum_h item[b][s][h] * w[s][k*HH+h'][h]   (bf16 in/out)
// Grid (128 s, 16 tiles): blockIdx.x = s -> all 16 tiles of one s land on the
// same XCD (id%8 = s%8), L2 captures the 4x input reuse. Staging reads are
// contiguous 128-B line segments from the transposed bf16 inputs.
// LDS: 128x64 bf16 per array, XOR-swizzled granules (proven conflict-free R3).
// A=w rows (d), B=item rows (b) => D rows are 4 consecutive h' -> ushort4.
// ---------------------------------------------------------------------------
__global__ __launch_bounds__(256) void einsum_mfma(
    const unsigned short* __restrict__ At,  // bf16 [S][B][H]
    const unsigned short* __restrict__ W,   // bf16 [S][D][H]
    unsigned short* __restrict__ hat)       // bf16 [B][K][S][H]
{
  __shared__ unsigned short Al[128 * 64];
  __shared__ unsigned short Wl[128 * 64];
  const int s  = blockIdx.x;
  const int b0 = (blockIdx.y & 3) * 128;
  const int dt = blockIdx.y >> 2;
  const int d0 = dt * 128;
  const int t  = threadIdx.x;
  const int lane = t & 63, wv = t >> 6;
  const int qm = wv & 1, qn = wv >> 1;
  const int n16 = lane & 15, kq = lane >> 4;
  const int sr = t >> 3, sc = t & 7;        // staging row-base / 16B col

  const unsigned short* Abase = At + ((size_t)s * BB + b0) * HH;
  const unsigned short* Wbase = W + ((size_t)s * DD + d0) * HH;

  f32x4 acc[4][4] = {};
  for (int ks = 0; ks < 128; ks += 64) {
    #pragma unroll
    for (int j = 0; j < 4; j++) {
      const int r = sr + 32 * j;
      uint4 va = *(const uint4*)(Abase + (size_t)r * HH + ks + sc * 8);
      uint4 vw = *(const uint4*)(Wbase + (size_t)r * HH + ks + sc * 8);
      const int goff = ((sc + r) & 7) * 8;
      *(uint4*)&Al[r * 64 + goff] = va;
      *(uint4*)&Wl[r * 64 + goff] = vw;
    }
    __syncthreads();
    #pragma unroll
    for (int kk = 0; kk < 2; kk++) {
      bf16x8 af[4], bfr[4];
      #pragma unroll
      for (int i = 0; i < 4; i++) {
        const int ra = qm * 64 + i * 16 + n16;   // w rows (h')
        const int rb = qn * 64 + i * 16 + n16;   // item rows (b)
        af[i]  = *(const bf16x8*)&Wl[ra * 64 + ((kk * 4 + kq + ra) & 7) * 8];
        bfr[i] = *(const bf16x8*)&Al[rb * 64 + ((kk * 4 + kq + rb) & 7) * 8];
      }
      #pragma unroll
      for (int i = 0; i < 4; i++)
        #pragma unroll
        for (int j = 0; j < 4; j++)
          acc[i][j] = __builtin_amdgcn_mfma_f32_16x16x32_bf16(af[i], bfr[j], acc[i][j], 0, 0, 0);
    }
    __syncthreads();
  }

  // D row = qm*64+i*16+kq*4+reg = h'; col = qn*64+j*16+n16 = local b
  #pragma unroll
  for (int j = 0; j < 4; j++) {
    const int b = b0 + qn * 64 + j * 16 + n16;
    unsigned short* orow = hat + (((size_t)b * KK + dt) * SS + s) * HH;
    #pragma unroll
    for (int i = 0; i < 4; i++) {
      const int h = qm * 64 + i * 16 + kq * 4;
      ushort4 o;
      o.x = f2bf(acc[i][j][0]); o.y = f2bf(acc[i][j][1]);
      o.z = f2bf(acc[i][j][2]); o.w = f2bf(acc[i][j][3]);
      *(ushort4*)(orow + h) = o;
    }
  }
}

// ---------------------------------------------------------------------------
// Batch-axis softmax (legacy torch dim=0) + mask zeroing. Grid (S,K).
// ---------------------------------------------------------------------------
__global__ __launch_bounds__(256) void softmax_k(
    const float* __restrict__ cw, const float* __restrict__ mask,
    float* __restrict__ sw)
{
  __shared__ float rbuf[4];
  const int s = blockIdx.x, k = blockIdx.y, t = threadIdx.x;
  const size_t base = ((size_t)k * SS + s) * BB;
  float v0 = cw[base + t], v1 = cw[base + 256 + t];
  float m = fmaxf(v0, v1);
  #pragma unroll
  for (int o = 32; o; o >>= 1) m = fmaxf(m, __shfl_xor(m, o));
  if ((t & 63) == 0) rbuf[t >> 6] = m;
  __syncthreads();
  m = fmaxf(fmaxf(rbuf[0], rbuf[1]), fmaxf(rbuf[2], rbuf[3]));
  float e0 = expf(v0 - m), e1 = expf(v1 - m);
  float ssum = e0 + e1;
  #pragma unroll
  for (int o = 32; o; o >>= 1) ssum += __shfl_xor(ssum, o);
  __syncthreads();
  if ((t & 63) == 0) rbuf[t >> 6] = ssum;
  __syncthreads();
  float inv = 1.f / (rbuf[0] + rbuf[1] + rbuf[2] + rbuf[3]);
  float m0 = mask[(size_t)t * SS + s];
  float m1 = mask[(size_t)(t + 256) * SS + s];
  sw[base + t]       = (m0 == 0.f) ? 0.f : e0 * inv;
  sw[base + 256 + t] = (m1 == 0.f) ? 0.f : e1 * inv;
}

// ---------------------------------------------------------------------------
// One routing iteration per (b,k). Stage the 32 KB bf16 hat slab in LDS ONCE
// (2048 uint4 = 8 per thread); both phases read from LDS.
//   mode 0: uniform sw from mask, cw  = delta
//   mode 1: sw from sw_in,        cw += delta
//   mode 2: sw from sw_in,        out = squash(cap)
// ---------------------------------------------------------------------------
__global__ __launch_bounds__(256) void routing_k(
    const unsigned short* __restrict__ hat, const float* __restrict__ mask,
    const float* __restrict__ sw_in, float* __restrict__ cw,
    float* __restrict__ out, int mode)
{
  __shared__ unsigned short hat_l[128 * 136];
  __shared__ float sw_l[128];
  __shared__ float4 red4[8][32];
  __shared__ float4 cq4[32];
  const int b = blockIdx.x, k = blockIdx.y, t = threadIdx.x;

  if (t < 128) {
    sw_l[t] = (mode == 0)
      ? ((mask[(size_t)b * SS + t] == 0.f) ? 0.f : (1.f / 512.f))
      : sw_in[((size_t)k * SS + t) * BB + b];
  }
  const uint4* hp = (const uint4*)(hat + ((size_t)b * KK + k) * SS * HH);
  #pragma unroll
  for (int j = 0; j < 8; j++) {            // 2048 uint4 total (bf16 slab!)
    const int f = t + 256 * j;
    const int s = f >> 4, c = f & 15;
    *(uint4*)&hat_l[s * 136 + c * 8] = hp[f];
  }
  __syncthreads();

  // phase 1: cap[h] = sum_s sw[s]*hat[s][h]; 8 s-groups x 32 uint2 cols
  {
    const int h4 = t & 31, sg = t >> 5;
    float4 a = make_float4(0.f, 0.f, 0.f, 0.f);
    #pragma unroll 4
    for (int i = 0; i < 16; i++) {
      const int s = sg * 16 + i;
      uint2 v = *(const uint2*)&hat_l[s * 136 + h4 * 4];
      float wv = sw_l[s];
      a.x = fmaf(wv, bflo(v.x), a.x);
      a.y = fmaf(wv, bfhi(v.x), a.y);
      a.z = fmaf(wv, bflo(v.y), a.z);
      a.w = fmaf(wv, bfhi(v.y), a.w);
    }
    red4[sg][h4] = a;
  }
  __syncthreads();

  if (t < 32) {
    float4 cap = red4[0][t];
    #pragma unroll
    for (int sg = 1; sg < 8; sg++) {
      float4 r = red4[sg][t];
      cap.x += r.x; cap.y += r.y; cap.z += r.z; cap.w += r.w;
    }
    float sq = cap.x * cap.x + cap.y * cap.y + cap.z * cap.z + cap.w * cap.w;
    #pragma unroll
    for (int o = 16; o; o >>= 1) sq += __shfl_xor(sq, o);
    const float n = sq;
    const float fac = n / (1.f + n) / sqrtf(n + 1e-9f);
    cap.x *= fac; cap.y *= fac; cap.z *= fac; cap.w *= fac;
    cq4[t] = cap;
    if (mode == 2)
      ((float4*)(out + ((size_t)b * KK + k) * HH))[t] = cap;
  }
  __syncthreads();

  if (mode < 2) {
    // phase 2: delta[s] = dot(hat[s][:], cq) — lane pair per s, from LDS
    const int s = t >> 1, hh = t & 1;
    const uint4* row = (const uint4*)&hat_l[s * 136 + hh * 64];
    float d = 0.f;
    #pragma unroll
    for (int j = 0; j < 8; j++) {
      uint4 v = row[j];
      float4 qa = cq4[hh * 16 + 2 * j];
      float4 qb = cq4[hh * 16 + 2 * j + 1];
      d += bflo(v.x) * qa.x + bfhi(v.x) * qa.y
         + bflo(v.y) * qa.z + bfhi(v.y) * qa.w
         + bflo(v.z) * qb.x + bfhi(v.z) * qb.y
         + bflo(v.w) * qb.z + bfhi(v.w) * qb.w;
    }
    d += __shfl_xor(d, 1);
    if (hh == 0) {
      float* p = cw + ((size_t)k * SS + s) * BB + b;
      if (mode == 0) *p = d; else *p += d;
    }
  }
}

extern "C" void kernel_launch(void* const* d_in, const int* in_sizes, int n_in,
                              void* d_out, int out_size, void* d_ws, size_t ws_size,
                              hipStream_t stream) {
  const float* item_eb = (const float*)d_in[0];   // [B,S,H]
  const float* mask    = (const float*)d_in[1];   // [B,S]
  const float* w       = (const float*)d_in[2];   // [1,S,K*H,H]
  float* out = (float*)d_out;                     // [B,K,H]

  char* ws = (char*)d_ws;
  unsigned short* hat_bf  = (unsigned short*)ws;               // 67.1 MB [B][K][S][H]
  unsigned short* item_t  = (unsigned short*)(ws + 67108864);  // 16.8 MB [S][B][H]
  unsigned short* w_bf    = (unsigned short*)(ws + 83886080);  // 16.8 MB [S][D][H]
  float* cw  = (float*)(ws + 100663296);                       // 1 MB [K][S][B]
  float* swb = (float*)(ws + 101711872);                       // 1 MB [K][S][B]

  prep_k<<<dim3(9216), 256, 0, stream>>>(item_eb, w, item_t, w_bf);
  einsum_mfma<<<dim3(128, 16), 256, 0, stream>>>(item_t, w_bf, hat_bf);

  routing_k<<<dim3(BB, KK), 256, 0, stream>>>(hat_bf, mask, nullptr, cw, out, 0);
  softmax_k<<<dim3(SS, KK), 256, 0, stream>>>(cw, mask, swb);
  routing_k<<<dim3(BB, KK), 256, 0, stream>>>(hat_bf, mask, swb, cw, out, 1);
  softmax_k<<<dim3(SS, KK), 256, 0, stream>>>(cw, mask, swb);
  routing_k<<<dim3(BB, KK), 256, 0, stream>>>(hat_bf, mask, swb, cw, out, 2);
}